// Round 8
// baseline (122.802 us; speedup 1.0000x reference)
//
#include <hip/hip_runtime.h>

// x: [B=16, T=16384, C=64] fp32. bp_sos/lp_sos: [2,6] fp32 rows (b0,b1,b2,a0,a1,a2; a0==1).
#define B_LEN 16
#define T_LEN 16384
#define C_LEN 64
#define CHUNK 64    // outputs per thread; amp 2.0x; 1024 blocks = 16 waves/CU
#define WARM  64    // zero-state warmup; transient ~0.83^64 ~ 7e-6 (empirically safe: absmax 0.0156)

// R13: hand-counted vmcnt pipeline (T4) via inline asm. Evidence: R3/R9/R12 all
// show memory time + VALU time ADDING (21.3 + ~7-10 = observed 30-34us) with
// zero overlap, invariant to store placement (R12's full store-deferral was a
// null). MLP arithmetic says HBM shouldn't bind (48-64KB outstanding/CU >> 9.2KB
// Little's-law need). Remaining actionable theory: the compiler waitcnt pass
// inserts conservative (deep/vmcnt(0)-ish) waits in the consume path -- the
// documented failure mode of source-level counted-vmcnt pipelines. Fix per the
// guide: take waitcnt emission away from the compiler.
//  - all input loads = inline-asm global_load_dword (8/group, imm offsets
//    0..1792 off one 64b base), so the waitcnt pass doesn't own them;
//  - every consume point = exact "s_waitcnt vmcnt(N)" + sched_barrier(0)
//    (rule #18: fence VALU hoisting past an asm waitcnt);
//  - static in-order FIFO accounting, stores included (8 regular stores per
//    emit phase, ack at L2): warm waits all vmcnt(24); emit waits
//    {24,32,40,48,48,40,32,24}. No wait ever drains below 24 outstanding.
// step() arithmetic order unchanged -> bit-identical output (absmax 0.015625).

#define LOADG(g) do {                                                     \
    asm volatile(                                                         \
        "global_load_dword %0, %8, off\n\t"                               \
        "global_load_dword %1, %8, off offset:256\n\t"                    \
        "global_load_dword %2, %8, off offset:512\n\t"                    \
        "global_load_dword %3, %8, off offset:768\n\t"                    \
        "global_load_dword %4, %8, off offset:1024\n\t"                   \
        "global_load_dword %5, %8, off offset:1280\n\t"                   \
        "global_load_dword %6, %8, off offset:1536\n\t"                   \
        "global_load_dword %7, %8, off offset:1792\n\t"                   \
        : "=&v"((g)[0]), "=&v"((g)[1]), "=&v"((g)[2]), "=&v"((g)[3]),     \
          "=&v"((g)[4]), "=&v"((g)[5]), "=&v"((g)[6]), "=&v"((g)[7])      \
        : "v"(lq) : "memory");                                            \
    lq += 8 * C_LEN;                                                      \
} while (0)

#define WAITV(n) do {                                                     \
    asm volatile("s_waitcnt vmcnt(" #n ")" ::: "memory");                 \
    __builtin_amdgcn_sched_barrier(0);                                    \
} while (0)

__global__ __launch_bounds__(256, 4) void iir_asm_kernel(
    const float* __restrict__ x,
    const float* __restrict__ bp,
    const float* __restrict__ lp,
    float* __restrict__ out)
{
    const int c     = threadIdx.x & 63;        // channel within batch
    const int bsub  = threadIdx.x >> 6;        // 0..3
    const int b     = blockIdx.y * 4 + bsub;   // batch 0..15
    const int chunk = blockIdx.x;              // 0..T/CHUNK-1

    // Uniform coefficients -> scalar (SGPR) loads. a's negated so updates are pure FMA.
    const float b10 = bp[0], b11 = bp[1], b12 = bp[2],  a11 = -bp[4],  a12 = -bp[5];
    const float b20 = bp[6], b21 = bp[7], b22 = bp[8],  a21 = -bp[10], a22 = -bp[11];
    const float b30 = lp[0], b31 = lp[1], b32 = lp[2],  a31 = -lp[4],  a32 = -lp[5];
    const float b40 = lp[6], b41 = lp[7], b42 = lp[8],  a41 = -lp[10], a42 = -lp[11];

    const int t_out0 = chunk * CHUNK;
    const int warm   = (t_out0 < WARM) ? t_out0 : WARM;  // 0 (chunk 0 only) or 64, uniform
    const int t0     = t_out0 - warm;

    // DF2T state: 2 per section
    float s11 = 0.f, s12 = 0.f;
    float s21 = 0.f, s22 = 0.f;
    float s31 = 0.f, s32 = 0.f;
    float s41 = 0.f, s42 = 0.f;

    const float* lq = x   + ((size_t)b * T_LEN + t0)     * C_LEN + c;
    float*       po = out + ((size_t)b * T_LEN + t_out0) * C_LEN + c;

    auto step = [&](float xn) -> float {
        // section 1 (bandpass)
        float y1 = fmaf(b10, xn, s11);
        s11 = fmaf(b11, xn, fmaf(a11, y1, s12));
        s12 = fmaf(b12, xn, a12 * y1);
        // section 2 (bandpass)
        float y2 = fmaf(b20, y1, s21);
        s21 = fmaf(b21, y1, fmaf(a21, y2, s22));
        s22 = fmaf(b22, y1, a22 * y2);
        // squaring nonlinearity
        float v = y2 * y2;
        // section 3 (lowpass)
        float y3 = fmaf(b30, v, s31);
        s31 = fmaf(b31, v, fmaf(a31, y3, s32));
        s32 = fmaf(b32, v, a32 * y3);
        // section 4 (lowpass)
        float y4 = fmaf(b40, y3, s41);
        s41 = fmaf(b41, y3, fmaf(a41, y4, s42));
        s42 = fmaf(b42, y3, a42 * y4);
        return y4;
    };

    // 4-group x 8-sample register ring; indices static after unroll.
    float P[4][8];

    // Prologue: 32 loads in flight (groups 0..3). No waits yet.
    LOADG(P[0]); LOADG(P[1]); LOADG(P[2]); LOADG(P[3]);

    // Warm: 8 phases, each {wait group i (24 younger loads in flight), consume 8,
    // reload group i -> samples for phase i+4}. Loads-only FIFO -> vmcnt(24) exact.
    if (warm) {
#pragma unroll
        for (int i = 0; i < 8; ++i) {
            WAITV(24);
#pragma unroll
            for (int j = 0; j < 8; ++j) step(P[i & 3][j]);   // discard; states advance
            LOADG(P[i & 3]);
        }
    }

    // Emit: 8 phases of {wait, compute+store 8, maybe reload}. Wait constants from
    // exact in-order accounting with 8 stores/phase issued BEFORE that phase's
    // reload: E0..E7 -> 24,32,40,48,48,40,32,24. Total loads = warm + CHUNK
    // samples, ending exactly at t_out0 + CHUNK <= T: no OOB.
#define EMIT_PHASE(K, N, DOLOAD) do {                                     \
        WAITV(N);                                                         \
        _Pragma("unroll")                                                 \
        for (int j = 0; j < 8; ++j)                                       \
            po[(K * 8 + j) * C_LEN] = step(P[K & 3][j]);                  \
        if (DOLOAD) LOADG(P[K & 3]);                                      \
    } while (0)

    EMIT_PHASE(0, 24, 1);
    EMIT_PHASE(1, 32, 1);
    EMIT_PHASE(2, 40, 1);
    EMIT_PHASE(3, 48, 1);
    EMIT_PHASE(4, 48, 0);
    EMIT_PHASE(5, 40, 0);
    EMIT_PHASE(6, 32, 0);
    EMIT_PHASE(7, 24, 0);
#undef EMIT_PHASE
}

extern "C" void kernel_launch(void* const* d_in, const int* in_sizes, int n_in,
                              void* d_out, int out_size, void* d_ws, size_t ws_size,
                              hipStream_t stream) {
    const float* x  = (const float*)d_in[0];
    const float* bp = (const float*)d_in[1];
    const float* lp = (const float*)d_in[2];
    float* out      = (float*)d_out;

    dim3 grid(T_LEN / CHUNK, B_LEN / 4);   // 256 x 4 = 1024 blocks -> 4 blocks/CU, 16 waves/CU
    dim3 block(256);                        // 4 waves: 4 batches x 64 channels
    iir_asm_kernel<<<grid, block, 0, stream>>>(x, bp, lp, out);
}

// Round 9
// 116.869 us; speedup vs baseline: 1.0508x; 1.0508x over previous
//
#include <hip/hip_runtime.h>

// x: [B=16, T=16384, C=64] fp32. bp_sos/lp_sos: [2,6] fp32 rows (b0,b1,b2,a0,a1,a2; a0==1).
#define B_LEN 16
#define T_LEN 16384
#define C_LEN 64
#define CHUNK 128   // warm amp 1.5x (R8)
#define WARM  64    // zero-state warmup; transient ~0.83^64 ~ 7e-6 (empirically safe: absmax 0.0156)

// R14 = R9 (best, ~30us) + bijective XCD swizzle (T1). Theory: the warm overlap
// makes ~1/3 of logical reads RE-READS of bytes fetched by the neighboring
// chunk's block. Default dispatch round-robins consecutive blocks across the 8
// XCDs (private, non-coherent L2s), so those re-reads are served by the L3 path
// (high latency, BW shared with HBM fills) -- explaining 4.5 TB/s effective vs
// 6.3 for re-read-free fills, and why store placement (R12), wait granularity
// (R13, regressed), and load width (R10) were all nulls.
// Swizzle: flat = x + gridX*y; swz = (flat%8)*(512/8) + flat/8  (bijective,
// 512%8==0, m204). XCD k gets 64 CONSECUTIVE work-ids = consecutive chunks of a
// batch row -> warm re-reads hit the local 4MB L2. Resident set per XCD:
// 64 blocks x 48KB span ~ 3MB < 4MB. Work mapping relabeled only; per-thread
// arithmetic identical -> absmax stays 0.015625 exactly.
__global__ __launch_bounds__(256, 2) void iir_pipe_kernel(
    const float* __restrict__ x,
    const float* __restrict__ bp,
    const float* __restrict__ lp,
    float* __restrict__ out)
{
    // ---- XCD-aware block swizzle (T1, bijective: 512 blocks % 8 XCDs == 0) ----
    const int flat  = blockIdx.x + gridDim.x * blockIdx.y;   // 0..511, round-robins XCDs
    const int swz   = (flat & 7) * 64 + (flat >> 3);         // contiguous runs per XCD
    const int chunk = swz & 127;                             // 0..127 along T
    const int ygrp  = swz >> 7;                              // 0..3 batch group

    const int c     = threadIdx.x & 63;        // channel within batch
    const int bsub  = threadIdx.x >> 6;        // 0..3
    const int b     = ygrp * 4 + bsub;         // batch 0..15

    // Uniform coefficients -> scalar (SGPR) loads. a's negated so updates are pure FMA.
    const float b10 = bp[0], b11 = bp[1], b12 = bp[2],  a11 = -bp[4],  a12 = -bp[5];
    const float b20 = bp[6], b21 = bp[7], b22 = bp[8],  a21 = -bp[10], a22 = -bp[11];
    const float b30 = lp[0], b31 = lp[1], b32 = lp[2],  a31 = -lp[4],  a32 = -lp[5];
    const float b40 = lp[6], b41 = lp[7], b42 = lp[8],  a41 = -lp[10], a42 = -lp[11];

    const int t_out0 = chunk * CHUNK;
    const int warm   = (t_out0 < WARM) ? t_out0 : WARM;  // 0 (chunk 0) or 64, block-uniform
    const int t0     = t_out0 - warm;

    // DF2T state: 2 per section
    float s11 = 0.f, s12 = 0.f;
    float s21 = 0.f, s22 = 0.f;
    float s31 = 0.f, s32 = 0.f;
    float s41 = 0.f, s42 = 0.f;

    const float* __restrict__ lq = x   + ((size_t)b * T_LEN + t0)     * C_LEN + c;
    float*       __restrict__ po = out + ((size_t)b * T_LEN + t_out0) * C_LEN + c;

    auto step = [&](float xn) -> float {
        // section 1 (bandpass)
        float y1 = fmaf(b10, xn, s11);
        s11 = fmaf(b11, xn, fmaf(a11, y1, s12));
        s12 = fmaf(b12, xn, a12 * y1);
        // section 2 (bandpass)
        float y2 = fmaf(b20, y1, s21);
        s21 = fmaf(b21, y1, fmaf(a21, y2, s22));
        s22 = fmaf(b22, y1, a22 * y2);
        // squaring nonlinearity
        float v = y2 * y2;
        // section 3 (lowpass)
        float y3 = fmaf(b30, v, s31);
        s31 = fmaf(b31, v, fmaf(a31, y3, s32));
        s32 = fmaf(b32, v, a32 * y3);
        // section 4 (lowpass)
        float y4 = fmaf(b40, y3, s41);
        s41 = fmaf(b41, y3, fmaf(a41, y4, s42));
        s42 = fmaf(b42, y3, a42 * y4);
        return y4;
    };

    // 4x8 register pipeline. All indices compile-time after unroll (no scratch).
    float P0[8], P1[8], P2[8], P3[8];

    auto load8 = [&](float* d) {
#pragma unroll
        for (int j = 0; j < 8; ++j) d[j] = lq[j * C_LEN];  // dword + imm offsets off one addr
        lq += 8 * C_LEN;
    };
    auto warm8 = [&](const float* d) {
#pragma unroll
        for (int j = 0; j < 8; ++j) step(d[j]);            // discard outputs
    };
    auto fence = [&]() { __builtin_amdgcn_sched_barrier(0); };

    // Emit phase: compute -> prefetch loads -> stores (stores LAST in vmcnt FIFO, R9).
    auto emit8_reload = [&](float* d) {
        float y[8];
#pragma unroll
        for (int j = 0; j < 8; ++j) y[j] = step(d[j]);
        load8(d);          // overwrites d; per-reg anti-dep lets load j trail step j
        fence();           // stores must not be scheduled above the loads
#pragma unroll
        for (int j = 0; j < 8; ++j)
            __builtin_nontemporal_store(y[j], po + j * C_LEN);
        po += 8 * C_LEN;
        fence();
    };
    auto emit8_final = [&](const float* d) {
        float y[8];
#pragma unroll
        for (int j = 0; j < 8; ++j) y[j] = step(d[j]);
#pragma unroll
        for (int j = 0; j < 8; ++j)
            __builtin_nontemporal_store(y[j], po + j * C_LEN);
        po += 8 * C_LEN;
        fence();
    };

    // Prologue: 32 samples in flight before the first dependent FMA.
    load8(P0); load8(P1); load8(P2); load8(P3);
    fence();

    // Warm phase: warm/32 rotations (0 or 2). {consume 8, reload 8}, fenced.
    const int nrot = warm >> 5;
    for (int r = 0; r < nrot; ++r) {
        warm8(P0); load8(P0); fence();
        warm8(P1); load8(P1); fence();
        warm8(P2); load8(P2); fence();
        warm8(P3); load8(P3); fence();
    }
    // Emit with reload: 3 rotations. Consume [warm+r*32, warm+(r+1)*32),
    // load [warm+(r+1)*32, warm+(r+2)*32). Total loads = warm + CHUNK, ending
    // exactly at t_out0 + CHUNK <= T: no OOB.
#pragma unroll 1
    for (int r = 0; r < (CHUNK - 32) / 32; ++r) {
        emit8_reload(P0);
        emit8_reload(P1);
        emit8_reload(P2);
        emit8_reload(P3);
    }
    // Final 32 samples: no further loads.
    emit8_final(P0);
    emit8_final(P1);
    emit8_final(P2);
    emit8_final(P3);
}

extern "C" void kernel_launch(void* const* d_in, const int* in_sizes, int n_in,
                              void* d_out, int out_size, void* d_ws, size_t ws_size,
                              hipStream_t stream) {
    const float* x  = (const float*)d_in[0];
    const float* bp = (const float*)d_in[1];
    const float* lp = (const float*)d_in[2];
    float* out      = (float*)d_out;

    dim3 grid(T_LEN / CHUNK, B_LEN / 4);   // 128 x 4 = 512 blocks -> 2 blocks/CU, 8 waves/CU
    dim3 block(256);                        // 4 waves: 4 batches x 64 channels
    iir_pipe_kernel<<<grid, block, 0, stream>>>(x, bp, lp, out);
}

// Round 10
// 111.950 us; speedup vs baseline: 1.0969x; 1.0439x over previous
//
#include <hip/hip_runtime.h>

// x: [B=16, T=16384, C=64] fp32. bp_sos/lp_sos: [2,6] fp32 rows (b0,b1,b2,a0,a1,a2; a0==1).
#define B_LEN 16
#define T_LEN 16384
#define C_LEN 64
#define CHUNK 128   // warm amp 1.5x (R8)
#define WARM  64    // zero-state warmup; transient ~0.83^64 ~ 7e-6 (empirically safe: absmax 0.0156)

// R15 = R9 with 16-sample phases (was 8). Unified model from R0-R14: per-wave
// elapsed = phases x ~3000cy, i.e. ~336 issue-cy + ~2600cy stall PER PHASE,
// invariant to store placement (R12 null), wait counting (R13 regressed), XCD
// mapping (R14 null), and wave count. That is a latency-like per-phase cost,
// not bandwidth (4.4 TB/s = 70% of copy ceiling). Discriminator: double the
// phase size -> halve the stall count per wave. 12 phases x (672+S) vs
// 24 x (336+S): if S is per-phase-fixed, K ~30 -> ~18-24us; if S is really
// bytes-proportional, K flat -> declare pattern ceiling next round.
// Ring: 4 groups x 16 samples (64 VGPR ring; ~110 total, fits 128-cap at
// launch_bounds(256,2)). Load/store sets, arithmetic order, and geometry
// otherwise identical to R9 -> absmax stays 0.015625 exactly.
__global__ __launch_bounds__(256, 2) void iir_pipe_kernel(
    const float* __restrict__ x,
    const float* __restrict__ bp,
    const float* __restrict__ lp,
    float* __restrict__ out)
{
    const int c     = threadIdx.x & 63;        // channel within batch
    const int bsub  = threadIdx.x >> 6;        // 0..3
    const int b     = blockIdx.y * 4 + bsub;   // batch 0..15
    const int chunk = blockIdx.x;              // 0..T/CHUNK-1

    // Uniform coefficients -> scalar (SGPR) loads. a's negated so updates are pure FMA.
    const float b10 = bp[0], b11 = bp[1], b12 = bp[2],  a11 = -bp[4],  a12 = -bp[5];
    const float b20 = bp[6], b21 = bp[7], b22 = bp[8],  a21 = -bp[10], a22 = -bp[11];
    const float b30 = lp[0], b31 = lp[1], b32 = lp[2],  a31 = -lp[4],  a32 = -lp[5];
    const float b40 = lp[6], b41 = lp[7], b42 = lp[8],  a41 = -lp[10], a42 = -lp[11];

    const int t_out0 = chunk * CHUNK;
    const int warm   = (t_out0 < WARM) ? t_out0 : WARM;  // 0 (chunk 0) or 64, block-uniform
    const int t0     = t_out0 - warm;

    // DF2T state: 2 per section
    float s11 = 0.f, s12 = 0.f;
    float s21 = 0.f, s22 = 0.f;
    float s31 = 0.f, s32 = 0.f;
    float s41 = 0.f, s42 = 0.f;

    const float* __restrict__ lq = x   + ((size_t)b * T_LEN + t0)     * C_LEN + c;
    float*       __restrict__ po = out + ((size_t)b * T_LEN + t_out0) * C_LEN + c;

    auto step = [&](float xn) -> float {
        // section 1 (bandpass)
        float y1 = fmaf(b10, xn, s11);
        s11 = fmaf(b11, xn, fmaf(a11, y1, s12));
        s12 = fmaf(b12, xn, a12 * y1);
        // section 2 (bandpass)
        float y2 = fmaf(b20, y1, s21);
        s21 = fmaf(b21, y1, fmaf(a21, y2, s22));
        s22 = fmaf(b22, y1, a22 * y2);
        // squaring nonlinearity
        float v = y2 * y2;
        // section 3 (lowpass)
        float y3 = fmaf(b30, v, s31);
        s31 = fmaf(b31, v, fmaf(a31, y3, s32));
        s32 = fmaf(b32, v, a32 * y3);
        // section 4 (lowpass)
        float y4 = fmaf(b40, y3, s41);
        s41 = fmaf(b41, y3, fmaf(a41, y4, s42));
        s42 = fmaf(b42, y3, a42 * y4);
        return y4;
    };

    // 4x16 register pipeline. All indices compile-time after unroll (no scratch).
    float P0[16], P1[16], P2[16], P3[16];

    auto load16 = [&](float* d) {
#pragma unroll
        for (int j = 0; j < 16; ++j) d[j] = lq[j * C_LEN]; // dword + imm offsets (<=3840)
        lq += 16 * C_LEN;
    };
    auto warm16 = [&](const float* d) {
#pragma unroll
        for (int j = 0; j < 16; ++j) step(d[j]);           // discard outputs
    };
    auto fence = [&]() { __builtin_amdgcn_sched_barrier(0); };

    // Emit phase: compute -> prefetch loads -> stores (stores LAST in vmcnt FIFO, R9).
    auto emit16_reload = [&](float* d) {
        float y[16];
#pragma unroll
        for (int j = 0; j < 16; ++j) y[j] = step(d[j]);
        load16(d);         // overwrites d; per-reg anti-dep lets load j trail step j
        fence();           // stores must not be scheduled above the loads
#pragma unroll
        for (int j = 0; j < 16; ++j)
            __builtin_nontemporal_store(y[j], po + j * C_LEN);
        po += 16 * C_LEN;
        fence();
    };
    auto emit16_final = [&](const float* d) {
        float y[16];
#pragma unroll
        for (int j = 0; j < 16; ++j) y[j] = step(d[j]);
#pragma unroll
        for (int j = 0; j < 16; ++j)
            __builtin_nontemporal_store(y[j], po + j * C_LEN);
        po += 16 * C_LEN;
        fence();
    };

    // Prologue: 64 samples in flight before the first dependent FMA.
    load16(P0); load16(P1); load16(P2); load16(P3);
    fence();

    // Warm phase: warm/64 rotations (0 or 1). {consume 16, reload 16}, fenced.
    const int nrot = warm >> 6;
#pragma unroll 1
    for (int r = 0; r < nrot; ++r) {
        warm16(P0); load16(P0); fence();
        warm16(P1); load16(P1); fence();
        warm16(P2); load16(P2); fence();
        warm16(P3); load16(P3); fence();
    }
    // Emit with reload: (CHUNK-64)/64 = 1 rotation. Consume [warm, warm+64),
    // load [warm+64, warm+128). Total loads = warm + CHUNK, ending exactly at
    // t_out0 + CHUNK <= T: no OOB.
#pragma unroll 1
    for (int r = 0; r < (CHUNK - 64) / 64; ++r) {
        emit16_reload(P0);
        emit16_reload(P1);
        emit16_reload(P2);
        emit16_reload(P3);
    }
    // Final 64 samples: no further loads.
    emit16_final(P0);
    emit16_final(P1);
    emit16_final(P2);
    emit16_final(P3);
}

extern "C" void kernel_launch(void* const* d_in, const int* in_sizes, int n_in,
                              void* d_out, int out_size, void* d_ws, size_t ws_size,
                              hipStream_t stream) {
    const float* x  = (const float*)d_in[0];
    const float* bp = (const float*)d_in[1];
    const float* lp = (const float*)d_in[2];
    float* out      = (float*)d_out;

    dim3 grid(T_LEN / CHUNK, B_LEN / 4);   // 128 x 4 = 512 blocks -> 2 blocks/CU, 8 waves/CU
    dim3 block(256);                        // 4 waves: 4 batches x 64 channels
    iir_pipe_kernel<<<grid, block, 0, stream>>>(x, bp, lp, out);
}